// Round 4
// baseline (29854.489 us; speedup 1.0000x reference)
//
#include <hip/hip_runtime.h>

#define H    51
#define G    153        // 3*H
#define BB   2048       // batch
#define TSEQ 1024       // input timesteps
#define NB   8          // batch rows per workgroup
#define NT   512        // 8 waves -> 2 waves/SIMD -> 256 VGPR cap
#define HP   52         // padded h row (f32), 208B = 13 x 16B
#define XS   308        // X row stride (306 used + pad)

__device__ __forceinline__ float sigm(float x) { return 1.0f / (1.0f + __expf(-x)); }
__device__ __forceinline__ float tanh_(float x) { return 1.0f - 2.0f / (__expf(2.0f * x) + 1.0f); }

struct SM {
    alignas(16) float h[2][NB][HP];   // h1, h2 (padded, [51] stays 0)
    alignas(16) float X[NB][XS];      // [0..152]: gh1 then gi2 ; [153..305]: gh2
    alignas(16) float xstep[NB][4];
    float olds[NB];
};

__global__ __launch_bounds__(NT, 2) void gru_persist(
    const float* __restrict__ inp, const int* __restrict__ fut,
    const float* __restrict__ wih1, const float* __restrict__ whh1,
    const float* __restrict__ bih1, const float* __restrict__ bhh1,
    const float* __restrict__ wih2, const float* __restrict__ whh2,
    const float* __restrict__ bih2, const float* __restrict__ bhh2,
    const float* __restrict__ wlin, const float* __restrict__ blin,
    float* __restrict__ out)
{
    __shared__ SM sm;
    const int t  = threadIdx.x;
    const int bg = blockIdx.x;

    // ---- roles ----
    // P1 (t<308): pair q=t>>1 in [0,154): 77 pairs layer0 then 77 pairs layer1
    //             (rows padded to 154/layer; pad row 153 store-guarded).
    //             bh=t&1 -> batches 4bh..4bh+3. 2 rows x 4 batches.
    const int  q    = t >> 1;
    const int  bh   = t & 1;
    const bool doP1 = (t < 308);
    const int  lay  = (q >= 77) ? 1 : 0;
    const int  plc  = min(q - 77 * lay, 76);       // clamped pair within layer
    const int  lr0  = 2 * plc;                     // always <=152 (valid)
    const int  lr1  = lr0 + 1;                     // ==153 only for pad pair
    const bool v1   = (lr1 < G);
    const int  growA = lay * G + lr0;
    const int  growB = growA + 1;
    // P5 (t<308): qq=t>>2 in [0,77): rows 2qq,2qq+1 of W_ih2 (padded to 154);
    //             bq=t&3 -> batches 2bq,2bq+1. 2 rows x 2 batches.
    const int  qq   = min(t >> 2, 76);
    const int  bq   = t & 3;
    const bool doP5 = (t < 308);
    const int  m0   = 2 * qq;                      // always <=152
    const int  m1   = m0 + 1;                      // ==153 only pad
    const bool v5   = (m1 < G);
    // elementwise (t<408): (be, je)
    const bool doE  = (t < 408);
    const int  be   = t / 51;
    const int  je   = t - be * 51;
    // P8 reduce (t<256)
    const int  br   = t >> 5;
    const int  sr   = t & 31;
    // x staging (t>=504)
    const bool doX  = (t >= 504);
    const int  bs   = t - 504;

    // ---- register-resident weights (208 VGPRs) ----
    float wA[HP], wB[HP], wC[HP], wD[HP];
    {
        const float* base1 = lay ? whh2 : whh1;
        const float* rA = base1 + lr0 * H;
        const float* rB = base1 + (v1 ? lr1 : lr0) * H;   // clamped, guarded at store
        const float* rC = wih2 + m0 * H;
        const float* rD = wih2 + (v5 ? m1 : m0) * H;
#pragma unroll
        for (int k = 0; k < H; ++k) {
            wA[k] = rA[k]; wB[k] = rB[k]; wC[k] = rC[k]; wD[k] = rD[k];
        }
        wA[51] = 0.f; wB[51] = 0.f; wC[51] = 0.f; wD[51] = 0.f;   // pad (h pad=0, avoid NaN)
    }
    // biases in registers
    const float bA = lay ? bhh2[lr0] : bhh1[lr0];
    const float bBr = lay ? bhh2[v1 ? lr1 : lr0] : bhh1[v1 ? lr1 : lr0];
    const float bC = bih2[m0];
    const float bD = bih2[v5 ? m1 : m0];
    // elementwise constants in registers
    const float wi_r = wih1[je], wi_z = wih1[je + H], wi_n = wih1[je + 2 * H];
    const float bi_r = bih1[je], bi_z = bih1[je + H], bi_n = bih1[je + 2 * H];
    // P8 constants
    const float wl0 = wlin[sr];
    const float wl1 = (sr + 32 < H) ? wlin[sr + 32] : 0.f;
    const float blin_r = blin[0];

    // ---- one-time LDS init ----
    for (int i = t; i < 2 * NB * HP; i += NT) ((float*)sm.h)[i] = 0.f;
    if (t < NB) sm.olds[t] = 0.f;

    const float* xrow = inp + (size_t)(bg * NB + (doX ? bs : 0)) * TSEQ;
    float4 xnxt = make_float4(0.f, 0.f, 0.f, 0.f);
    if (doX) xnxt = *(const float4*)(xrow);       // x[0..3]
    __syncthreads();

    const int TT = TSEQ + fut[0];

    for (int ts = 0; ts < TT; ++ts) {
        // ---- x staging (overlaps P1) ----
        if (doX && ts < TSEQ && (ts & 3) == 0) {
            *(float4*)&sm.xstep[bs][0] = xnxt;
            if (ts + 4 < TSEQ) xnxt = *(const float4*)(xrow + ts + 4);
        }
        // ---- P1: gh1 = W_hh1 h1 + b_hh1 ; gh2 = W_hh2 h2 + b_hh2 ----
        if (doP1) {
            const int b0 = 4 * bh;
            float accA[4], accB[4];
#pragma unroll
            for (int bi = 0; bi < 4; ++bi) {
                const float4* hp = (const float4*)&sm.h[lay][b0 + bi][0];
                float aA = 0.f, aB = 0.f;
#pragma unroll
                for (int k4 = 0; k4 < 13; ++k4) {
                    float4 v = hp[k4];
                    aA = fmaf(wA[4*k4  ], v.x, aA); aA = fmaf(wA[4*k4+1], v.y, aA);
                    aA = fmaf(wA[4*k4+2], v.z, aA); aA = fmaf(wA[4*k4+3], v.w, aA);
                    aB = fmaf(wB[4*k4  ], v.x, aB); aB = fmaf(wB[4*k4+1], v.y, aB);
                    aB = fmaf(wB[4*k4+2], v.z, aB); aB = fmaf(wB[4*k4+3], v.w, aB);
                }
                accA[bi] = aA; accB[bi] = aB;
            }
#pragma unroll
            for (int bi = 0; bi < 4; ++bi) {
                sm.X[b0 + bi][growA] = accA[bi] + bA;
                if (v1) sm.X[b0 + bi][growB] = accB[bi] + bBr;
            }
        }
        __syncthreads();

        // ---- P3: GRU1 elementwise -> h1' ----
        if (doE) {
            float xv = (ts < TSEQ) ? sm.xstep[be][ts & 3] : sm.olds[be];
            float gr = sigm(fmaf(xv, wi_r, bi_r) + sm.X[be][je]);
            float gz = sigm(fmaf(xv, wi_z, bi_z) + sm.X[be][je + H]);
            float gn = tanh_(fmaf(gr, sm.X[be][je + 2 * H], fmaf(xv, wi_n, bi_n)));
            float ho = sm.h[0][be][je];
            sm.h[0][be][je] = (1.0f - gz) * gn + gz * ho;
        }
        __syncthreads();

        // ---- P5: gi2 = W_ih2 h1' + b_ih2 (overwrites gh1 region of X) ----
        if (doP5) {
            const int b0 = 2 * bq;
            float accC[2], accD[2];
#pragma unroll
            for (int bi = 0; bi < 2; ++bi) {
                const float4* hp = (const float4*)&sm.h[0][b0 + bi][0];
                float aC = 0.f, aD = 0.f;
#pragma unroll
                for (int k4 = 0; k4 < 13; ++k4) {
                    float4 v = hp[k4];
                    aC = fmaf(wC[4*k4  ], v.x, aC); aC = fmaf(wC[4*k4+1], v.y, aC);
                    aC = fmaf(wC[4*k4+2], v.z, aC); aC = fmaf(wC[4*k4+3], v.w, aC);
                    aD = fmaf(wD[4*k4  ], v.x, aD); aD = fmaf(wD[4*k4+1], v.y, aD);
                    aD = fmaf(wD[4*k4+2], v.z, aD); aD = fmaf(wD[4*k4+3], v.w, aD);
                }
                accC[bi] = aC; accD[bi] = aD;
            }
#pragma unroll
            for (int bi = 0; bi < 2; ++bi) {
                sm.X[b0 + bi][m0] = accC[bi] + bC;
                if (v5) sm.X[b0 + bi][m1] = accD[bi] + bD;
            }
        }
        __syncthreads();

        // ---- P7: GRU2 elementwise -> h2' ----
        if (doE) {
            float gr = sigm(sm.X[be][je]         + sm.X[be][G + je]);
            float gz = sigm(sm.X[be][je + H]     + sm.X[be][G + je + H]);
            float gn = tanh_(fmaf(gr, sm.X[be][G + je + 2 * H], sm.X[be][je + 2 * H]));
            float ho = sm.h[1][be][je];
            sm.h[1][be][je] = (1.0f - gz) * gn + gz * ho;
        }
        __syncthreads();

        // ---- P8: out = w_lin . h2' + b_lin (no trailing barrier; overlaps next P1) ----
        if (t < 256) {
            float p = wl0 * sm.h[1][br][sr];
            p = fmaf(wl1, sm.h[1][br][(sr + 32 < H) ? (sr + 32) : sr], p) - ((sr + 32 < H) ? 0.f : wl1 * sm.h[1][br][sr]);
            // simpler: wl1 is 0 when sr+32>=H, so the fma adds 0; rewrite cleanly:
            p = wl0 * sm.h[1][br][sr];
            if (sr + 32 < H) p = fmaf(wl1, sm.h[1][br][sr + 32], p);
            p += __shfl_xor(p, 1);
            p += __shfl_xor(p, 2);
            p += __shfl_xor(p, 4);
            p += __shfl_xor(p, 8);
            p += __shfl_xor(p, 16);
            if (sr == 0) {
                float o = p + blin_r;
                sm.olds[br] = o;                       // read by P3 only after next barrier
                out[(size_t)(bg * NB + br) * TT + ts] = o;
            }
        }
    }
}

extern "C" void kernel_launch(void* const* d_in, const int* in_sizes, int n_in,
                              void* d_out, int out_size, void* d_ws, size_t ws_size,
                              hipStream_t stream) {
    (void)in_sizes; (void)n_in; (void)d_ws; (void)ws_size; (void)out_size;
    gru_persist<<<BB / NB, NT, 0, stream>>>(
        (const float*)d_in[0], (const int*)d_in[1],
        (const float*)d_in[2], (const float*)d_in[3], (const float*)d_in[4], (const float*)d_in[5],
        (const float*)d_in[6], (const float*)d_in[7], (const float*)d_in[8], (const float*)d_in[9],
        (const float*)d_in[10], (const float*)d_in[11],
        (float*)d_out);
}

// Round 5
// 4496.457 us; speedup vs baseline: 6.6396x; 6.6396x over previous
//
#include <hip/hip_runtime.h>

#define H    51
#define G    153        // 3*H
#define BB   2048       // batch
#define TSEQ 1024       // input timesteps
#define NB   8          // batch rows per workgroup
#define NT   512        // 8 waves
#define WPD  52         // padded weight/h row length (f32): 208B, 16B-aligned
#define XS   308        // X row stride per batch

__device__ __forceinline__ float sigm(float x) { return 1.0f / (1.0f + __expf(-x)); }
__device__ __forceinline__ float tanh_(float x) { return 1.0f - 2.0f / (__expf(2.0f * x) + 1.0f); }

struct SM {
    float W[459 * WPD];            // rows 0..152 whh1, 153..305 whh2, 306..458 wih2 ([51] pad = 0)
    float hT[2][WPD][NB];          // hidden, transposed: [layer][k][batch]; hT[*][51][*] = 0
    float X[NB * XS];              // gates: X[b*XS + r]; r<153: gh1/gi2, 153..305: gh2
    alignas(16) float xstep[NB][4];
    float olds[NB];
};

// row-dot: acc over all 8 batches; w per-lane distinct rows, h wave-broadcast
__device__ __forceinline__ void mv8(const float* __restrict__ wrow,
                                    const float* __restrict__ hb,
                                    float* __restrict__ xcol, float bias) {
    float2 a01 = {0.f, 0.f}, a23 = {0.f, 0.f}, a45 = {0.f, 0.f}, a67 = {0.f, 0.f};
#pragma unroll
    for (int k4 = 0; k4 < 13; ++k4) {
        float4 w4 = *(const float4*)(wrow + 4 * k4);
#pragma unroll
        for (int j = 0; j < 4; ++j) {
            float wk = (j == 0) ? w4.x : (j == 1) ? w4.y : (j == 2) ? w4.z : w4.w;
            float4 hA = *(const float4*)(hb + (4 * k4 + j) * NB);       // batches 0..3
            float4 hB = *(const float4*)(hb + (4 * k4 + j) * NB + 4);   // batches 4..7
            a01.x = fmaf(wk, hA.x, a01.x); a01.y = fmaf(wk, hA.y, a01.y);
            a23.x = fmaf(wk, hA.z, a23.x); a23.y = fmaf(wk, hA.w, a23.y);
            a45.x = fmaf(wk, hB.x, a45.x); a45.y = fmaf(wk, hB.y, a45.y);
            a67.x = fmaf(wk, hB.z, a67.x); a67.y = fmaf(wk, hB.w, a67.y);
        }
    }
    xcol[0 * XS] = a01.x + bias; xcol[1 * XS] = a01.y + bias;
    xcol[2 * XS] = a23.x + bias; xcol[3 * XS] = a23.y + bias;
    xcol[4 * XS] = a45.x + bias; xcol[5 * XS] = a45.y + bias;
    xcol[6 * XS] = a67.x + bias; xcol[7 * XS] = a67.y + bias;
}

__global__ __launch_bounds__(NT, 1) void gru_persist(
    const float* __restrict__ inp, const int* __restrict__ fut,
    const float* __restrict__ wih1, const float* __restrict__ whh1,
    const float* __restrict__ bih1, const float* __restrict__ bhh1,
    const float* __restrict__ wih2, const float* __restrict__ whh2,
    const float* __restrict__ bih2, const float* __restrict__ bhh2,
    const float* __restrict__ wlin, const float* __restrict__ blin,
    float* __restrict__ out)
{
    extern __shared__ char smraw[];
    SM& sm = *reinterpret_cast<SM*>(smraw);
    const int t  = threadIdx.x;
    const int bg = blockIdx.x;

    // ---- roles ----
    const bool doP1 = (t < 306);               // row t of [whh1; whh2]
    const bool doP5 = (t < 153);               // row t of wih2
    const bool doE  = (t < 408);               // elementwise (be, je)
    const int  be   = t / 51;
    const int  je   = t - be * 51;
    const int  br   = t >> 5, sr = t & 31;     // P8 (t<256)
    const bool doX  = (t >= 504);              // x staging
    const int  bs   = t - 504;

    // ---- per-thread constants (registers; small, spill-proof) ----
    const int   r1c   = (t < 306) ? t : 305;
    const float bias1 = (r1c < G) ? bhh1[r1c] : bhh2[r1c - G];
    const int   r5c   = (t < 153) ? t : 152;
    const float bias5 = bih2[r5c];
    const float wi_r = wih1[je], wi_z = wih1[je + H], wi_n = wih1[je + 2 * H];
    const float bi_r = bih1[je], bi_z = bih1[je + H], bi_n = bih1[je + 2 * H];
    const float wl0 = wlin[sr];
    const float wl1 = (sr + 32 < H) ? wlin[sr + 32] : 0.f;
    const int   sr2 = (sr + 32 < H) ? (sr + 32) : sr;
    const float blin_r = blin[0];

    // ---- one-time LDS staging ----
    for (int idx = t; idx < 459 * H; idx += NT) {
        int r = idx / H, k = idx - r * H;
        float v = (r < G) ? whh1[idx] : (r < 2 * G) ? whh2[idx - G * H] : wih2[idx - 2 * G * H];
        sm.W[r * WPD + k] = v;
    }
    for (int r = t; r < 459; r += NT) sm.W[r * WPD + H] = 0.f;   // pad col
    for (int i = t; i < 2 * WPD * NB; i += NT) ((float*)sm.hT)[i] = 0.f;
    if (t < NB) sm.olds[t] = 0.f;

    // ---- per-thread LDS pointers (computed once) ----
    const float* wrow1 = &sm.W[r1c * WPD];
    const float* hb1   = &sm.hT[(r1c < G) ? 0 : 1][0][0];
    float*       xcol1 = &sm.X[r1c];
    const float* wrow5 = &sm.W[(306 + r5c) * WPD];
    const float* hb5   = &sm.hT[0][0][0];
    float*       xcol5 = &sm.X[r5c];
    float*       Xe    = &sm.X[be * XS];

    const float* xrow = inp + (size_t)(bg * NB + (doX ? bs : 0)) * TSEQ;
    float4 xnxt = make_float4(0.f, 0.f, 0.f, 0.f);
    if (doX) xnxt = *(const float4*)(xrow);
    __syncthreads();

    const int TT = TSEQ + fut[0];

    for (int ts = 0; ts < TT; ++ts) {
        // ---- x staging (overlaps P1) ----
        if (doX && ts < TSEQ && (ts & 3) == 0) {
            *(float4*)&sm.xstep[bs][0] = xnxt;
            if (ts + 4 < TSEQ) xnxt = *(const float4*)(xrow + ts + 4);
        }
        // ---- P1: gh1 rows 0..152 (h1), gh2 rows 153..305 (h2) ----
        if (doP1) mv8(wrow1, hb1, xcol1, bias1);
        __syncthreads();

        // ---- P3: GRU1 elementwise -> h1' (transposed store) ----
        if (doE) {
            float xv = (ts < TSEQ) ? sm.xstep[be][ts & 3] : sm.olds[be];
            float gr = sigm(fmaf(xv, wi_r, bi_r) + Xe[je]);
            float gz = sigm(fmaf(xv, wi_z, bi_z) + Xe[je + H]);
            float gn = tanh_(fmaf(gr, Xe[je + 2 * H], fmaf(xv, wi_n, bi_n)));
            float ho = sm.hT[0][je][be];
            sm.hT[0][je][be] = (1.0f - gz) * gn + gz * ho;
        }
        __syncthreads();

        // ---- P5: gi2 = W_ih2 h1' (overwrites X[b][0..152]) ----
        if (doP5) mv8(wrow5, hb5, xcol5, bias5);
        __syncthreads();

        // ---- P7: GRU2 elementwise -> h2' ----
        if (doE) {
            float gr = sigm(Xe[je]         + Xe[G + je]);
            float gz = sigm(Xe[je + H]     + Xe[G + je + H]);
            float gn = tanh_(fmaf(gr, Xe[G + je + 2 * H], Xe[je + 2 * H]));
            float ho = sm.hT[1][je][be];
            sm.hT[1][je][be] = (1.0f - gz) * gn + gz * ho;
        }
        __syncthreads();

        // ---- P8: out = w_lin . h2' + b_lin (no trailing barrier; overlaps next P1) ----
        if (t < 256) {
            float p = wl0 * sm.hT[1][sr][br];
            p = fmaf(wl1, sm.hT[1][sr2][br], p);
            p += __shfl_xor(p, 1);
            p += __shfl_xor(p, 2);
            p += __shfl_xor(p, 4);
            p += __shfl_xor(p, 8);
            p += __shfl_xor(p, 16);
            if (sr == 0) {
                float o = p + blin_r;
                sm.olds[br] = o;                        // read by P3 only after next barrier
                out[(size_t)(bg * NB + br) * TT + ts] = o;
            }
        }
    }
}

extern "C" void kernel_launch(void* const* d_in, const int* in_sizes, int n_in,
                              void* d_out, int out_size, void* d_ws, size_t ws_size,
                              hipStream_t stream) {
    (void)in_sizes; (void)n_in; (void)d_ws; (void)ws_size; (void)out_size;
    hipFuncSetAttribute(reinterpret_cast<const void*>(gru_persist),
                        hipFuncAttributeMaxDynamicSharedMemorySize, (int)sizeof(SM));
    gru_persist<<<BB / NB, NT, sizeof(SM), stream>>>(
        (const float*)d_in[0], (const int*)d_in[1],
        (const float*)d_in[2], (const float*)d_in[3], (const float*)d_in[4], (const float*)d_in[5],
        (const float*)d_in[6], (const float*)d_in[7], (const float*)d_in[8], (const float*)d_in[9],
        (const float*)d_in[10], (const float*)d_in[11],
        (float*)d_out);
}

// Round 6
// 1758.335 us; speedup vs baseline: 16.9788x; 2.5572x over previous
//
#include <hip/hip_runtime.h>

#define H    51
#define G    153
#define BB   2048
#define TSEQ 1024
#define NB   8
#define NT   512        // 8 waves
#define KP   72         // hT bf16 row stride (144B, 16B-aligned)
#define XS   340        // X row stride (floats, /4 for 16B align)

typedef __attribute__((ext_vector_type(8))) short short8;   // 8 bf16 = one MFMA operand
typedef __attribute__((ext_vector_type(4))) float f32x4;

__device__ __forceinline__ float sigm(float x) { return 1.0f / (1.0f + __expf(-x)); }
__device__ __forceinline__ float tanh_(float x) { return 1.0f - 2.0f / (__expf(2.0f * x) + 1.0f); }
__device__ __forceinline__ unsigned short f2bf(float f) {
    unsigned u = __float_as_uint(f);
    return (unsigned short)((u + 0x7fffu + ((u >> 16) & 1u)) >> 16);   // RNE
}
__device__ __forceinline__ float bf2f(unsigned short s) { return __uint_as_float(((unsigned)s) << 16); }

struct SM {
    alignas(16) short h1hi[16][KP];   // h1 split-bf16, [batch(16, 8 used)][k(72, 51 used)]
    alignas(16) short h1lo[16][KP];
    alignas(16) short h2hi[16][KP];
    alignas(16) short h2lo[16][KP];
    alignas(16) float h1f[NB][56];    // exact f32 hidden
    alignas(16) float h2f[NB][56];
    alignas(16) float X[NB][XS];      // [0..152]: gh1 then gi2 ; [160..312]: gh2
    alignas(16) float xstep[NB][4];
    float olds[NB];
};

__global__ __launch_bounds__(NT) void gru_persist(
    const float* __restrict__ inp, const int* __restrict__ fut,
    const float* __restrict__ wih1, const float* __restrict__ whh1,
    const float* __restrict__ bih1, const float* __restrict__ bhh1,
    const float* __restrict__ wih2, const float* __restrict__ whh2,
    const float* __restrict__ bih2, const float* __restrict__ bhh2,
    const float* __restrict__ wlin, const float* __restrict__ blin,
    float* __restrict__ out)
{
    __shared__ SM sm;
    const int t    = threadIdx.x;
    const int bg   = blockIdx.x;
    const int wv   = t >> 6;          // wave 0..7
    const int lane = t & 63;
    const int n    = lane & 15;       // MFMA col = batch
    const int q    = lane >> 4;       // quad 0..3

    // ---- elementwise / reduce roles ----
    const bool doE = (t < 408);
    const int  tcl = doE ? t : 407;
    const int  be  = tcl / 51;
    const int  je  = tcl - be * 51;
    const int  br  = t >> 5, sr = t & 31;           // P8 (t<256)
    const bool doX = (t >= 504);
    const int  bs  = t - 504;

    // ---- A-fragments (weights) preloaded into registers, once ----
    // P1: 20 M-tiles. waves 0..3 -> tiles {w,w+4,w+8}<10 (gh1, B=h1);
    //     waves 4..7 -> tiles {10+(w-4)+4tt}<20 (gh2, B=h2).
    short8 a1hi[3][2], a1lo[3][2];
    f32x4  b1v[3];
    short8 a5hi[2][2], a5lo[2][2];
    f32x4  b5v[2];

#pragma unroll
    for (int tt = 0; tt < 3; ++tt) {
        const int  T  = (wv < 4) ? (wv + 4 * tt) : (10 + (wv - 4) + 4 * tt);
        const bool tv = (wv < 4) ? (T < 10) : (T < 20);
        const int  r  = T * 16 + n;
        const float* src = nullptr;
        if (tv) {
            if (r < G) src = whh1 + r * H;
            else if (r >= 160 && r < 160 + G) src = whh2 + (r - 160) * H;
        }
#pragma unroll
        for (int kb = 0; kb < 2; ++kb) {
#pragma unroll
            for (int j = 0; j < 8; ++j) {
                const int k = kb * 32 + q * 8 + j;
                const float x = (src != nullptr && k < H) ? src[k] : 0.f;
                const unsigned short hb = f2bf(x);
                a1hi[tt][kb][j] = (short)hb;
                a1lo[tt][kb][j] = (short)f2bf(x - bf2f(hb));
            }
        }
        f32x4 bv = {0.f, 0.f, 0.f, 0.f};
#pragma unroll
        for (int rg = 0; rg < 4; ++rg) {
            const int rr = T * 16 + 4 * q + rg;
            float b = 0.f;
            if (tv) {
                if (rr < G) b = bhh1[rr];
                else if (rr >= 160 && rr < 160 + G) b = bhh2[rr - 160];
            }
            bv[rg] = b;
        }
        b1v[tt] = bv;
    }
    // P5: 10 M-tiles over 8 waves: tiles {w, w+8}<10; B=h1'.
#pragma unroll
    for (int tt = 0; tt < 2; ++tt) {
        const int  T  = wv + 8 * tt;
        const bool tv = (T < 10);
        const int  r  = T * 16 + n;
        const float* src = (tv && r < G) ? (wih2 + r * H) : nullptr;
#pragma unroll
        for (int kb = 0; kb < 2; ++kb) {
#pragma unroll
            for (int j = 0; j < 8; ++j) {
                const int k = kb * 32 + q * 8 + j;
                const float x = (src != nullptr && k < H) ? src[k] : 0.f;
                const unsigned short hb = f2bf(x);
                a5hi[tt][kb][j] = (short)hb;
                a5lo[tt][kb][j] = (short)f2bf(x - bf2f(hb));
            }
        }
        f32x4 bv = {0.f, 0.f, 0.f, 0.f};
#pragma unroll
        for (int rg = 0; rg < 4; ++rg) {
            const int rr = T * 16 + 4 * q + rg;
            bv[rg] = (tv && rr < G) ? bih2[rr] : 0.f;
        }
        b5v[tt] = bv;
    }

    // ---- elementwise / output constants ----
    const float wi_r = wih1[je], wi_z = wih1[je + H], wi_n = wih1[je + 2 * H];
    const float bi_r = bih1[je], bi_z = bih1[je + H], bi_n = bih1[je + 2 * H];
    const float wl0 = wlin[sr];
    const float wl1 = (sr + 32 < H) ? wlin[sr + 32] : 0.f;
    const int   sr2 = (sr + 32 < H) ? (sr + 32) : sr;
    const float blin_r = blin[0];

    // ---- LDS zero-init ----
    for (int i = t; i < 16 * KP; i += NT) {
        sm.h1hi[0][i] = 0; sm.h1lo[0][i] = 0; sm.h2hi[0][i] = 0; sm.h2lo[0][i] = 0;
    }
    for (int i = t; i < NB * 56; i += NT) { ((float*)sm.h1f)[i] = 0.f; ((float*)sm.h2f)[i] = 0.f; }
    if (t < NB) sm.olds[t] = 0.f;

    const float* xrow = inp + (size_t)(bg * NB + (doX ? bs : 0)) * TSEQ;
    float4 xnxt = make_float4(0.f, 0.f, 0.f, 0.f);
    if (doX) xnxt = *(const float4*)(xrow);
    __syncthreads();

    const int TT = TSEQ + fut[0];

    for (int ts = 0; ts < TT; ++ts) {
        // ---- x staging (overlaps P1) ----
        if (doX && ts < TSEQ && (ts & 3) == 0) {
            *(float4*)&sm.xstep[bs][0] = xnxt;
            if (ts + 4 < TSEQ) xnxt = *(const float4*)(xrow + ts + 4);
        }
        // ---- P1: gh1 (tiles<10, B=h1) / gh2 (tiles>=10, B=h2) via MFMA ----
        {
            short8 bh0, bh1, bl0, bl1;
            if (wv < 4) {
                bh0 = *(const short8*)&sm.h1hi[n][q * 8];
                bh1 = *(const short8*)&sm.h1hi[n][32 + q * 8];
                bl0 = *(const short8*)&sm.h1lo[n][q * 8];
                bl1 = *(const short8*)&sm.h1lo[n][32 + q * 8];
            } else {
                bh0 = *(const short8*)&sm.h2hi[n][q * 8];
                bh1 = *(const short8*)&sm.h2hi[n][32 + q * 8];
                bl0 = *(const short8*)&sm.h2lo[n][q * 8];
                bl1 = *(const short8*)&sm.h2lo[n][32 + q * 8];
            }
#pragma unroll
            for (int tt = 0; tt < 3; ++tt) {
                const int  T  = (wv < 4) ? (wv + 4 * tt) : (10 + (wv - 4) + 4 * tt);
                const bool tv = (wv < 4) ? (T < 10) : (T < 20);
                if (tv) {
                    f32x4 acc = {0.f, 0.f, 0.f, 0.f};
                    acc = __builtin_amdgcn_mfma_f32_16x16x32_bf16(a1lo[tt][0], bh0, acc, 0, 0, 0);
                    acc = __builtin_amdgcn_mfma_f32_16x16x32_bf16(a1hi[tt][0], bl0, acc, 0, 0, 0);
                    acc = __builtin_amdgcn_mfma_f32_16x16x32_bf16(a1hi[tt][0], bh0, acc, 0, 0, 0);
                    acc = __builtin_amdgcn_mfma_f32_16x16x32_bf16(a1lo[tt][1], bh1, acc, 0, 0, 0);
                    acc = __builtin_amdgcn_mfma_f32_16x16x32_bf16(a1hi[tt][1], bl1, acc, 0, 0, 0);
                    acc = __builtin_amdgcn_mfma_f32_16x16x32_bf16(a1hi[tt][1], bh1, acc, 0, 0, 0);
                    if (n < NB) {
                        f32x4 o = acc + b1v[tt];
                        *(f32x4*)&sm.X[n][T * 16 + 4 * q] = o;
                    }
                }
            }
        }
        __syncthreads();

        // ---- P3: GRU1 elementwise -> h1' + bf16 split ----
        if (doE) {
            const float xv = (ts < TSEQ) ? sm.xstep[be][ts & 3] : sm.olds[be];
            const float gr = sigm(fmaf(xv, wi_r, bi_r) + sm.X[be][je]);
            const float gz = sigm(fmaf(xv, wi_z, bi_z) + sm.X[be][je + H]);
            const float gn = tanh_(fmaf(gr, sm.X[be][je + 2 * H], fmaf(xv, wi_n, bi_n)));
            const float ho = sm.h1f[be][je];
            const float hn = (1.0f - gz) * gn + gz * ho;
            sm.h1f[be][je] = hn;
            const unsigned short hb = f2bf(hn);
            sm.h1hi[be][je] = (short)hb;
            sm.h1lo[be][je] = (short)f2bf(hn - bf2f(hb));
        }
        __syncthreads();

        // ---- P5: gi2 = W_ih2 h1' + b_ih2 via MFMA (overwrites X[.][0..159]) ----
        {
            const short8 bh0 = *(const short8*)&sm.h1hi[n][q * 8];
            const short8 bh1 = *(const short8*)&sm.h1hi[n][32 + q * 8];
            const short8 bl0 = *(const short8*)&sm.h1lo[n][q * 8];
            const short8 bl1 = *(const short8*)&sm.h1lo[n][32 + q * 8];
#pragma unroll
            for (int tt = 0; tt < 2; ++tt) {
                const int T = wv + 8 * tt;
                if (T < 10) {
                    f32x4 acc = {0.f, 0.f, 0.f, 0.f};
                    acc = __builtin_amdgcn_mfma_f32_16x16x32_bf16(a5lo[tt][0], bh0, acc, 0, 0, 0);
                    acc = __builtin_amdgcn_mfma_f32_16x16x32_bf16(a5hi[tt][0], bl0, acc, 0, 0, 0);
                    acc = __builtin_amdgcn_mfma_f32_16x16x32_bf16(a5hi[tt][0], bh0, acc, 0, 0, 0);
                    acc = __builtin_amdgcn_mfma_f32_16x16x32_bf16(a5lo[tt][1], bh1, acc, 0, 0, 0);
                    acc = __builtin_amdgcn_mfma_f32_16x16x32_bf16(a5hi[tt][1], bl1, acc, 0, 0, 0);
                    acc = __builtin_amdgcn_mfma_f32_16x16x32_bf16(a5hi[tt][1], bh1, acc, 0, 0, 0);
                    if (n < NB) {
                        f32x4 o = acc + b5v[tt];
                        *(f32x4*)&sm.X[n][T * 16 + 4 * q] = o;
                    }
                }
            }
        }
        __syncthreads();

        // ---- P7: GRU2 elementwise -> h2' + bf16 split ----
        if (doE) {
            const float gr = sigm(sm.X[be][je]         + sm.X[be][160 + je]);
            const float gz = sigm(sm.X[be][je + H]     + sm.X[be][160 + je + H]);
            const float gn = tanh_(fmaf(gr, sm.X[be][160 + je + 2 * H], sm.X[be][je + 2 * H]));
            const float ho = sm.h2f[be][je];
            const float hn = (1.0f - gz) * gn + gz * ho;
            sm.h2f[be][je] = hn;
            const unsigned short hb = f2bf(hn);
            sm.h2hi[be][je] = (short)hb;
            sm.h2lo[be][je] = (short)f2bf(hn - bf2f(hb));
        }
        __syncthreads();

        // ---- P8: out = w_lin . h2' + b_lin (no trailing barrier; overlaps next P1) ----
        if (t < 256) {
            float p = wl0 * sm.h2f[br][sr];
            p = fmaf(wl1, sm.h2f[br][sr2], p);
            p += __shfl_xor(p, 1);
            p += __shfl_xor(p, 2);
            p += __shfl_xor(p, 4);
            p += __shfl_xor(p, 8);
            p += __shfl_xor(p, 16);
            if (sr == 0) {
                const float o = p + blin_r;
                sm.olds[br] = o;                        // read by P3 only after next barrier
                out[(size_t)(bg * NB + br) * TT + ts] = o;
            }
        }
    }
}

extern "C" void kernel_launch(void* const* d_in, const int* in_sizes, int n_in,
                              void* d_out, int out_size, void* d_ws, size_t ws_size,
                              hipStream_t stream) {
    (void)in_sizes; (void)n_in; (void)d_ws; (void)ws_size; (void)out_size;
    gru_persist<<<BB / NB, NT, 0, stream>>>(
        (const float*)d_in[0], (const int*)d_in[1],
        (const float*)d_in[2], (const float*)d_in[3], (const float*)d_in[4], (const float*)d_in[5],
        (const float*)d_in[6], (const float*)d_in[7], (const float*)d_in[8], (const float*)d_in[9],
        (const float*)d_in[10], (const float*)d_in[11],
        (float*)d_out);
}

// Round 7
// 1732.470 us; speedup vs baseline: 17.2323x; 1.0149x over previous
//
#include <hip/hip_runtime.h>

#define H    51
#define G    153
#define BB   2048
#define TSEQ 1024
#define NB   8
#define NT   512        // 8 waves, 2/SIMD -> 256 VGPR cap
#define KP   72         // bf16 h-row stride (144B, 16B-aligned)

typedef __attribute__((ext_vector_type(8))) short short8;
typedef __attribute__((ext_vector_type(4))) float f32x4;

__device__ __forceinline__ float sigm(float x) { return 1.0f / (1.0f + __expf(-x)); }
__device__ __forceinline__ float tanh_(float x) { return 1.0f - 2.0f / (__expf(2.0f * x) + 1.0f); }
__device__ __forceinline__ unsigned short f2bf(float f) {
    unsigned u = __float_as_uint(f);
    return (unsigned short)((u + 0x7fffu + ((u >> 16) & 1u)) >> 16);   // RNE
}
__device__ __forceinline__ float bf2f(unsigned short s) { return __uint_as_float(((unsigned)s) << 16); }

#define MFMA(a, b, c) __builtin_amdgcn_mfma_f32_16x16x32_bf16((a), (b), (c), 0, 0, 0)

struct SM {
    alignas(16) short h1[2][16][KP];   // parity-buffered h1 (bf16-hi), [n][k]
    alignas(16) short h2[16][KP];      // h2 (bf16-hi)
    alignas(16) float part[8][8];      // out partials [wave][batch]
    alignas(16) float xstep[2][8][4];  // parity-buffered 4-step x chunks
    float olds[8];
};

// A-frags (hi/lo split) for tile T of a gate-stacked [3H][H] matrix, triple-padded rows:
// padded row 16T+n -> element j=4T+(n>>2), gate c=n&3 (c==3 or j>=H: zero row)
__device__ __forceinline__ void loadA(const float* __restrict__ src, int T, int n, int q,
                                      short8* ah, short8* al) {
    const int jt = 4 * T + (n >> 2);
    const int c  = n & 3;
    const bool rv = (c < 3) && (jt < H);
#pragma unroll
    for (int kb = 0; kb < 2; ++kb) {
        short8 hi, lo;
#pragma unroll
        for (int jj = 0; jj < 8; ++jj) {
            const int k = kb * 32 + q * 8 + jj;
            const float v = (rv && k < H) ? src[(c * H + jt) * H + k] : 0.f;
            const unsigned short hb = f2bf(v);
            hi[jj] = (short)hb;
            lo[jj] = (short)f2bf(v - bf2f(hb));
        }
        ah[kb] = hi; al[kb] = lo;
    }
}

__global__ __launch_bounds__(NT, 2) void gru_persist(
    const float* __restrict__ inp, const int* __restrict__ fut,
    const float* __restrict__ wih1, const float* __restrict__ whh1,
    const float* __restrict__ bih1, const float* __restrict__ bhh1,
    const float* __restrict__ wih2, const float* __restrict__ whh2,
    const float* __restrict__ bih2, const float* __restrict__ bhh2,
    const float* __restrict__ wlin, const float* __restrict__ blin,
    float* __restrict__ out)
{
    __shared__ SM sm;
    const int t = threadIdx.x, bg = blockIdx.x;
    const int w = t >> 6, lane = t & 63;
    const int n = lane & 15, q = lane >> 4;
    const int  T0 = w, T1 = w + 8;
    const bool v1 = (T1 <= 12);
    const int  j0 = 4 * T0 + q;                   // <= 31, always < H
    const int  j1 = 4 * T1 + q;
    const bool e0 = (n < NB);
    const bool e1 = v1 && (j1 < H) && (n < NB);

    // ---- A-fragments (registers, loaded once) ----
    short8 a1h0[2], a1l0[2], a1h1[2], a1l1[2];    // gh1 = whh1
    short8 a2h0[2], a2l0[2], a2h1[2], a2l1[2];    // gh2 = whh2
    short8 a3h0[2], a3l0[2], a3h1[2], a3l1[2];    // gi2 = wih2
    loadA(whh1, T0, n, q, a1h0, a1l0);
    loadA(whh1, T1, n, q, a1h1, a1l1);
    loadA(whh2, T0, n, q, a2h0, a2l0);
    loadA(whh2, T1, n, q, a2h1, a2l1);
    loadA(wih2, T0, n, q, a3h0, a3l0);
    loadA(wih2, T1, n, q, a3h1, a3l1);

    // ---- per-lane constants ----
    const int jc0 = j0;                            // valid
    const int jc1 = (v1 && j1 < H) ? j1 : (H - 1); // clamped
    const float b1r0 = bhh1[jc0], b1z0 = bhh1[H + jc0], b1n0 = bhh1[2 * H + jc0];
    const float b1r1 = bhh1[jc1], b1z1 = bhh1[H + jc1], b1n1 = bhh1[2 * H + jc1];
    const float wir0 = wih1[jc0], wiz0 = wih1[H + jc0], win0 = wih1[2 * H + jc0];
    const float wir1 = wih1[jc1], wiz1 = wih1[H + jc1], win1 = wih1[2 * H + jc1];
    const float bir0 = bih1[jc0], biz0 = bih1[H + jc0], bin0 = bih1[2 * H + jc0];
    const float bir1 = bih1[jc1], biz1 = bih1[H + jc1], bin1 = bih1[2 * H + jc1];
    const float b2r0 = bhh2[jc0], b2z0 = bhh2[H + jc0], b2n0 = bhh2[2 * H + jc0];
    const float b2r1 = bhh2[jc1], b2z1 = bhh2[H + jc1], b2n1 = bhh2[2 * H + jc1];
    const float c2r0 = bih2[jc0], c2z0 = bih2[H + jc0], c2n0 = bih2[2 * H + jc0];
    const float c2r1 = bih2[jc1], c2z1 = bih2[H + jc1], c2n1 = bih2[2 * H + jc1];
    const float wl0 = wlin[jc0], wl1v = wlin[jc1];
    const float blin_r = blin[0];

    // ---- LDS zero-init ----
    for (int i = t; i < 2 * 16 * KP; i += NT) ((short*)sm.h1)[i] = 0;
    for (int i = t; i < 16 * KP; i += NT) ((short*)sm.h2)[i] = 0;
    if (t < 64) ((float*)sm.part)[t] = 0.f;
    if (t < 8) sm.olds[t] = 0.f;

    // ---- x staging (wave 7, lanes q==3 & n>=8: e-inactive lanes) ----
    const bool doX = (w == 7) && (q == 3) && (n >= 8);
    const int  bs  = n - 8;
    const float* xrow = inp + (size_t)(bg * NB + (doX ? bs : 0)) * TSEQ;
    float4 xnxt = make_float4(0.f, 0.f, 0.f, 0.f);
    if (doX) {
        *(float4*)&sm.xstep[0][bs][0] = *(const float4*)xrow;   // steps 0..3
        xnxt = *(const float4*)(xrow + 4);                      // steps 4..7
    }
    float h1o0 = 0.f, h1o1 = 0.f, h2o0 = 0.f, h2o1 = 0.f;
    __syncthreads();

    const int TT = TSEQ + fut[0];

    for (int ts = 0; ts < TT; ++ts) {
        const int p = ts & 1;

        // ---- previous step's output reduction (wave 0) ----
        if (w == 0 && ts > 0) {
            float pp = ((const float*)sm.part)[lane];           // [v=lane>>3][b=lane&7]
            pp += __shfl_xor(pp, 8);
            pp += __shfl_xor(pp, 16);
            pp += __shfl_xor(pp, 32);
            if (lane < 8) {
                const float o = pp + blin_r;
                sm.olds[lane] = o;
                out[(size_t)(bg * NB + lane) * TT + (ts - 1)] = o;
            }
        }
        if (ts >= TSEQ) __syncthreads();    // olds feedback needed by E1

        // ================= phase A =================
        const short8 b1k0 = *(const short8*)&sm.h1[p][n][q * 8];
        const short8 b1k1 = *(const short8*)&sm.h1[p][n][32 + q * 8];
        const short8 b2k0 = *(const short8*)&sm.h2[n][q * 8];
        const short8 b2k1 = *(const short8*)&sm.h2[n][32 + q * 8];
        const float xv = (ts < TSEQ) ? sm.xstep[(ts >> 2) & 1][n & 7][ts & 3] : sm.olds[n & 7];

        // gh2 (held across barrier in registers)
        float g2r0, g2z0, g2n0, g2r1 = 0.f, g2z1 = 0.f, g2n1 = 0.f;
        {
            f32x4 g = {0.f, 0.f, 0.f, 0.f};
            g = MFMA(a2l0[0], b2k0, g); g = MFMA(a2l0[1], b2k1, g);
            g = MFMA(a2h0[0], b2k0, g); g = MFMA(a2h0[1], b2k1, g);
            g2r0 = g.x + b2r0; g2z0 = g.y + b2z0; g2n0 = g.z + b2n0;
        }
        if (v1) {
            f32x4 g = {0.f, 0.f, 0.f, 0.f};
            g = MFMA(a2l1[0], b2k0, g); g = MFMA(a2l1[1], b2k1, g);
            g = MFMA(a2h1[0], b2k0, g); g = MFMA(a2h1[1], b2k1, g);
            g2r1 = g.x + b2r1; g2z1 = g.y + b2z1; g2n1 = g.z + b2n1;
        }

        // gh1 + GRU1 elementwise, slot 0
        {
            f32x4 acc = {0.f, 0.f, 0.f, 0.f};
            acc = MFMA(a1l0[0], b1k0, acc); acc = MFMA(a1l0[1], b1k1, acc);
            acc = MFMA(a1h0[0], b1k0, acc); acc = MFMA(a1h0[1], b1k1, acc);
            const float gr = sigm(fmaf(xv, wir0, bir0) + acc.x + b1r0);
            const float gz = sigm(fmaf(xv, wiz0, biz0) + acc.y + b1z0);
            const float gn = tanh_(fmaf(gr, acc.z + b1n0, fmaf(xv, win0, bin0)));
            const float hn = (1.f - gz) * gn + gz * h1o0; h1o0 = hn;
            if (e0) sm.h1[p ^ 1][n][j0] = (short)f2bf(hn);
        }
        if (v1) {
            f32x4 acc = {0.f, 0.f, 0.f, 0.f};
            acc = MFMA(a1l1[0], b1k0, acc); acc = MFMA(a1l1[1], b1k1, acc);
            acc = MFMA(a1h1[0], b1k0, acc); acc = MFMA(a1h1[1], b1k1, acc);
            const float gr = sigm(fmaf(xv, wir1, bir1) + acc.x + b1r1);
            const float gz = sigm(fmaf(xv, wiz1, biz1) + acc.y + b1z1);
            const float gn = tanh_(fmaf(gr, acc.z + b1n1, fmaf(xv, win1, bin1)));
            const float hn = (1.f - gz) * gn + gz * h1o1; h1o1 = hn;
            if (e1) sm.h1[p ^ 1][n][j1] = (short)f2bf(hn);
        }
        __syncthreads();

        // ================= phase B =================
        const short8 c1k0 = *(const short8*)&sm.h1[p ^ 1][n][q * 8];
        const short8 c1k1 = *(const short8*)&sm.h1[p ^ 1][n][32 + q * 8];
        float pout = 0.f;
        {
            f32x4 acc = {0.f, 0.f, 0.f, 0.f};
            acc = MFMA(a3l0[0], c1k0, acc); acc = MFMA(a3l0[1], c1k1, acc);
            acc = MFMA(a3h0[0], c1k0, acc); acc = MFMA(a3h0[1], c1k1, acc);
            const float gr = sigm(acc.x + c2r0 + g2r0);
            const float gz = sigm(acc.y + c2z0 + g2z0);
            const float gn = tanh_(fmaf(gr, g2n0, acc.z + c2n0));
            const float hn = (1.f - gz) * gn + gz * h2o0; h2o0 = hn;
            if (e0) { sm.h2[n][j0] = (short)f2bf(hn); pout = wl0 * hn; }
        }
        if (v1) {
            f32x4 acc = {0.f, 0.f, 0.f, 0.f};
            acc = MFMA(a3l1[0], c1k0, acc); acc = MFMA(a3l1[1], c1k1, acc);
            acc = MFMA(a3h1[0], c1k0, acc); acc = MFMA(a3h1[1], c1k1, acc);
            const float gr = sigm(acc.x + c2r1 + g2r1);
            const float gz = sigm(acc.y + c2z1 + g2z1);
            const float gn = tanh_(fmaf(gr, g2n1, acc.z + c2n1));
            const float hn = (1.f - gz) * gn + gz * h2o1; h2o1 = hn;
            if (e1) { sm.h2[n][j1] = (short)f2bf(hn); pout = fmaf(wl1v, hn, pout); }
        }
        // per-wave output partial: sum over q (bits 4,5 of lane)
        pout += __shfl_xor(pout, 16);
        pout += __shfl_xor(pout, 32);
        if (q == 0 && n < NB) sm.part[w][n] = pout;

        // x staging for next 4 steps (parity buffer)
        if (doX && (ts & 3) == 3 && ts + 1 < TSEQ) {
            *(float4*)&sm.xstep[((ts + 1) >> 2) & 1][bs][0] = xnxt;
            if (ts + 8 < TSEQ) xnxt = *(const float4*)(xrow + ts + 5);
        }
        __syncthreads();
    }

    // ---- final step's output ----
    if (w == 0) {
        float pp = ((const float*)sm.part)[lane];
        pp += __shfl_xor(pp, 8);
        pp += __shfl_xor(pp, 16);
        pp += __shfl_xor(pp, 32);
        if (lane < 8) out[(size_t)(bg * NB + lane) * TT + (TT - 1)] = pp + blin_r;
    }
}

extern "C" void kernel_launch(void* const* d_in, const int* in_sizes, int n_in,
                              void* d_out, int out_size, void* d_ws, size_t ws_size,
                              hipStream_t stream) {
    (void)in_sizes; (void)n_in; (void)d_ws; (void)ws_size; (void)out_size;
    gru_persist<<<BB / NB, NT, 0, stream>>>(
        (const float*)d_in[0], (const int*)d_in[1],
        (const float*)d_in[2], (const float*)d_in[3], (const float*)d_in[4], (const float*)d_in[5],
        (const float*)d_in[6], (const float*)d_in[7], (const float*)d_in[8], (const float*)d_in[9],
        (const float*)d_in[10], (const float*)d_in[11],
        (float*)d_out);
}